// Round 1
// baseline (902.572 us; speedup 1.0000x reference)
//
#include <hip/hip_runtime.h>
#include <math.h>

#define B_ 4
#define T_ 2048
#define C_ 768
#define DK_ 96
#define NA_ 8
#define M_ (B_*T_)      /* 8192 */
#define K2_ (2*C_)      /* 1536 */
#define NCH_ 16         /* EMA chunks */
#define CK_ 128         /* EMA chunk len */

typedef __attribute__((ext_vector_type(8))) _Float16 half8;
typedef __attribute__((ext_vector_type(4))) float floatx4;

__device__ __forceinline__ float sigm(float x){ return 1.f/(1.f + expf(-x)); }
__device__ __forceinline__ unsigned enc_max(float f){
  unsigned i = __float_as_uint(f);
  return (i & 0x80000000u) ? ~i : (i | 0x80000000u);
}
__device__ __forceinline__ float dec_max(unsigned u){
  unsigned i = (u & 0x80000000u) ? (u & 0x7FFFFFFFu) : ~u;
  return __uint_as_float(i);
}
__device__ __forceinline__ float alpha_of(const float* tau){
  return expf(-log1pf(expf(tau[0])));
}

// ---------------- casts ----------------
__global__ void k_cast(const float* __restrict__ src, _Float16* __restrict__ dst, int n){
  int i = blockIdx.x*256 + threadIdx.x;
  int stride = gridDim.x*256;
  for (; i < n; i += stride) dst[i] = (_Float16)src[i];
}

// dst rows x (2*cols): [s0_row | s1_row]
__global__ void k_cast_cat(const float* __restrict__ s0, const float* __restrict__ s1,
                           _Float16* __restrict__ dst, int cols){
  int r = blockIdx.x;
  for (int c = threadIdx.x; c < cols; c += blockDim.x){
    dst[(size_t)r*2*cols + c]        = (_Float16)s0[(size_t)r*cols + c];
    dst[(size_t)r*2*cols + cols + c] = (_Float16)s1[(size_t)r*cols + c];
  }
}

// xcat[:, :C] = f16(x)
__global__ void k_xcat_x(const float* __restrict__ x, _Float16* __restrict__ xcat){
  int row = blockIdx.y;
  int c = blockIdx.x*256 + threadIdx.x;   // grid.x = 3 -> c < 768 always
  xcat[(size_t)row*K2_ + c] = (_Float16)x[(size_t)row*C_ + c];
}

// ---------------- EMA (chunked scan) ----------------
// pass1 over x (fp32) -> chunk sums
__global__ void k_ema_gate_p1(const float* __restrict__ x, const float* __restrict__ tau,
                              float* __restrict__ S){
  float al = alpha_of(tau);
  int b = blockIdx.x >> 4, ch = blockIdx.x & 15;
  const float* xp = x + (size_t)(b*T_ + ch*CK_)*C_;
  int c = threadIdx.x;
  float s0=0.f, s1=0.f, s2=0.f;
  for (int t = 0; t < CK_; ++t){
    const float* r = xp + (size_t)t*C_;
    s0 = al*s0 + r[c]; s1 = al*s1 + r[c+256]; s2 = al*s2 + r[c+512];
  }
  float* o = S + (size_t)blockIdx.x*C_;
  o[c]=s0; o[c+256]=s1; o[c+512]=s2;
}

// exclusive prefix over chunks
__global__ void k_ema_p2(const float* __restrict__ S, float* __restrict__ H,
                         const float* __restrict__ tau, float ckpow){
  float sp = log1pf(expf(tau[0]));
  float aCK = expf(-ckpow*sp);
  int b = blockIdx.x;
  for (int c = threadIdx.x; c < C_; c += 256){
    float h = 0.f;
    for (int ch = 0; ch < NCH_; ++ch){
      size_t idx = (size_t)(b*NCH_ + ch)*C_ + c;
      H[idx] = h;
      h = aCK*h + S[idx];
    }
  }
}

// pass3: gate EMA -> f16 into xcat[:, C:]
__global__ void k_ema_gate_p3(const float* __restrict__ x, const float* __restrict__ tau,
                              const float* __restrict__ H, _Float16* __restrict__ xcat){
  float al = alpha_of(tau);
  int b = blockIdx.x >> 4, ch = blockIdx.x & 15;
  const float* xp = x + (size_t)(b*T_ + ch*CK_)*C_;
  _Float16* op = xcat + (size_t)(b*T_ + ch*CK_)*K2_ + C_;
  int c = threadIdx.x;
  const float* hp = H + (size_t)blockIdx.x*C_;
  float h0 = hp[c], h1 = hp[c+256], h2 = hp[c+512];
  for (int t = 0; t < CK_; ++t){
    const float* r = xp + (size_t)t*C_;
    h0 = al*h0 + r[c]; h1 = al*h1 + r[c+256]; h2 = al*h2 + r[c+512];
    _Float16* o = op + (size_t)t*K2_;
    o[c]=(_Float16)h0; o[c+256]=(_Float16)h1; o[c+512]=(_Float16)h2;
  }
}

// fused fast+slow pass1: b_f = xp*wf, b_s = xp*ws (f16 inputs)
__global__ void k_ema_fs_p1(const _Float16* __restrict__ xp, const _Float16* __restrict__ wf,
                            const _Float16* __restrict__ ws,
                            const float* __restrict__ tf, const float* __restrict__ ts,
                            float* __restrict__ Sf, float* __restrict__ Ss){
  float af = alpha_of(tf), as = alpha_of(ts);
  int b = blockIdx.x >> 4, ch = blockIdx.x & 15;
  size_t base = (size_t)(b*T_ + ch*CK_)*C_;
  int c = threadIdx.x;
  float f0=0,f1=0,f2=0, s0=0,s1=0,s2=0;
  for (int t = 0; t < CK_; ++t){
    size_t o = base + (size_t)t*C_ + c;
    float p0=(float)xp[o], p1=(float)xp[o+256], p2=(float)xp[o+512];
    f0 = af*f0 + p0*(float)wf[o];     s0 = as*s0 + p0*(float)ws[o];
    f1 = af*f1 + p1*(float)wf[o+256]; s1 = as*s1 + p1*(float)ws[o+256];
    f2 = af*f2 + p2*(float)wf[o+512]; s2 = as*s2 + p2*(float)ws[o+512];
  }
  float* of = Sf + (size_t)blockIdx.x*C_;
  float* os = Ss + (size_t)blockIdx.x*C_;
  of[c]=f0; of[c+256]=f1; of[c+512]=f2;
  os[c]=s0; os[c+256]=s1; os[c+512]=s2;
}

// fused fast+slow pass3: out = f16(h*cg + delta)
__global__ void k_ema_fs_p3(const _Float16* __restrict__ xp, const _Float16* __restrict__ wf,
                            const _Float16* __restrict__ ws,
                            const float* __restrict__ tf, const float* __restrict__ ts,
                            const float* __restrict__ Hf, const float* __restrict__ Hs,
                            const unsigned* __restrict__ cgE, const float* __restrict__ delta,
                            _Float16* __restrict__ cf, _Float16* __restrict__ cs){
  float af = alpha_of(tf), as = alpha_of(ts);
  int b = blockIdx.x >> 4, ch = blockIdx.x & 15;
  size_t base = (size_t)(b*T_ + ch*CK_)*C_;
  int c = threadIdx.x;
  const float* dp = delta + (size_t)b*C_;
  float d0 = dp[c], d1 = dp[c+256], d2 = dp[c+512];
  const float* hfp = Hf + (size_t)blockIdx.x*C_;
  const float* hsp = Hs + (size_t)blockIdx.x*C_;
  float f0=hfp[c], f1=hfp[c+256], f2=hfp[c+512];
  float s0=hsp[c], s1=hsp[c+256], s2=hsp[c+512];
  const unsigned* cgp = cgE + (size_t)b*T_ + ch*CK_;
  for (int t = 0; t < CK_; ++t){
    size_t o = base + (size_t)t*C_ + c;
    float cgv = sigm(dec_max(cgp[t]));
    float p0=(float)xp[o], p1=(float)xp[o+256], p2=(float)xp[o+512];
    f0 = af*f0 + p0*(float)wf[o];     s0 = as*s0 + p0*(float)ws[o];
    f1 = af*f1 + p1*(float)wf[o+256]; s1 = as*s1 + p1*(float)ws[o+256];
    f2 = af*f2 + p2*(float)wf[o+512]; s2 = as*s2 + p2*(float)ws[o+512];
    cf[o]     = (_Float16)(f0*cgv + d0);
    cf[o+256] = (_Float16)(f1*cgv + d1);
    cf[o+512] = (_Float16)(f2*cgv + d2);
    cs[o]     = (_Float16)(s0*cgv + d0);
    cs[o+256] = (_Float16)(s1*cgv + d1);
    cs[o+512] = (_Float16)(s2*cgv + d2);
  }
}

// ---------------- GEMM: out = act(A @ W^T + bias) (+epilogue modes) ----------------
// A: MxK f16 row-major, W: NxK f16 row-major. K % 64 == 0.
#define BM 128
#define BN 128
#define BKg 64
#define LDK 72   /* BKg + 8 pad (f16 elems) -> 144B row, 16B aligned */

__global__ __launch_bounds__(256,2) void k_gemm(
    const _Float16* __restrict__ A, const _Float16* __restrict__ W,
    const float* __restrict__ bias, int M, int N, int K,
    int act,  // 0 none, 1 tanh, 2 sigmoid
    int mode, // 0 f32 store, 1 f16 store, 2 blend: out=aux+bl*(z-aux), 3 mul: out=z*aux
    float* __restrict__ outF, _Float16* __restrict__ outB,
    const float* __restrict__ aux, const float* __restrict__ blendp)
{
  __shared__ _Float16 As[BM*LDK];
  __shared__ _Float16 Ws[BN*LDK];
  int tid = threadIdx.x;
  int m0 = blockIdx.x * BM;
  int n0 = blockIdx.y * BN;
  int wave = tid >> 6, lane = tid & 63;
  int wr = wave >> 1, wc = wave & 1;
  int lr = lane & 15, lq = lane >> 4;
  floatx4 acc[4][4] = {};
  for (int k0 = 0; k0 < K; k0 += BKg){
    #pragma unroll
    for (int r = 0; r < 4; ++r){
      int ci = tid + r*256;          // 0..1023
      int row = ci >> 3, kp = ci & 7;
      uint4 va = make_uint4(0,0,0,0);
      int gr = m0 + row;
      if (gr < M) va = *(const uint4*)(A + (size_t)gr*K + k0 + kp*8);
      *(uint4*)(&As[row*LDK + kp*8]) = va;
      uint4 vw = make_uint4(0,0,0,0);
      int gn = n0 + row;
      if (gn < N) vw = *(const uint4*)(W + (size_t)gn*K + k0 + kp*8);
      *(uint4*)(&Ws[row*LDK + kp*8]) = vw;
    }
    __syncthreads();
    #pragma unroll
    for (int ks = 0; ks < 2; ++ks){
      half8 fa[4], fb[4];
      #pragma unroll
      for (int i = 0; i < 4; ++i){
        fa[i] = *(const half8*)(&As[(wr*64 + i*16 + lr)*LDK + ks*32 + lq*8]);
        fb[i] = *(const half8*)(&Ws[(wc*64 + i*16 + lr)*LDK + ks*32 + lq*8]);
      }
      #pragma unroll
      for (int i = 0; i < 4; ++i)
        #pragma unroll
        for (int j = 0; j < 4; ++j)
          acc[i][j] = __builtin_amdgcn_mfma_f32_16x16x32_f16(fa[i], fb[j], acc[i][j], 0, 0, 0);
    }
    __syncthreads();
  }
  float bl = 0.f;
  if (mode == 2) bl = sigm(blendp[0]);
  #pragma unroll
  for (int i = 0; i < 4; ++i){
    #pragma unroll
    for (int j = 0; j < 4; ++j){
      int col = n0 + wc*64 + j*16 + lr;
      if (col >= N) continue;
      float bv = bias ? bias[col] : 0.f;
      #pragma unroll
      for (int r = 0; r < 4; ++r){
        int row = m0 + wr*64 + i*16 + lq*4 + r;
        if (row >= M) continue;
        float z = acc[i][j][r] + bv;
        if (act == 1) z = tanhf(z);
        else if (act == 2) z = sigm(z);
        size_t oidx = (size_t)row*N + col;
        if (mode == 0) outF[oidx] = z;
        else if (mode == 1) outB[oidx] = (_Float16)z;
        else if (mode == 2){ float g = aux[oidx]; outF[oidx] = g + bl*(z - g); }
        else outF[oidx] = z * aux[oidx];
      }
    }
  }
}

// ---------------- causal max-score (MFMA) ----------------
#define SLDK 104  /* 96 + 8 pad f16 -> 208B row */
__global__ __launch_bounds__(256,2) void k_score(
    const _Float16* __restrict__ q, const _Float16* __restrict__ kv,
    unsigned* __restrict__ cgE)
{
  __shared__ _Float16 Qs[128*SLDK];
  __shared__ _Float16 Ks[128*SLDK];
  int b = blockIdx.y;
  int p = blockIdx.x;
  int ti = (int)((sqrtf(8.f*p + 1.f) - 1.f)*0.5f);
  while ((ti+1)*(ti+2)/2 <= p) ++ti;
  while (ti*(ti+1)/2 > p) --ti;
  int sj = p - ti*(ti+1)/2;

  int tid = threadIdx.x;
  const _Float16* qg = q  + (size_t)(b*T_ + ti*128)*DK_;
  const _Float16* kg = kv + (size_t)(b*T_ + sj*128)*DK_;
  #pragma unroll
  for (int r = 0; r < 6; ++r){
    int ci = tid + r*256;            // 0..1535
    int row = ci / 12, kp = ci % 12;
    *(uint4*)(&Qs[row*SLDK + kp*8]) = *(const uint4*)(qg + (size_t)row*DK_ + kp*8);
    *(uint4*)(&Ks[row*SLDK + kp*8]) = *(const uint4*)(kg + (size_t)row*DK_ + kp*8);
  }
  __syncthreads();

  int wave = tid >> 6, lane = tid & 63;
  int wr = wave >> 1, wc = wave & 1;
  int lr = lane & 15, lq = lane >> 4;
  floatx4 acc[4][4] = {};
  #pragma unroll
  for (int ks = 0; ks < 3; ++ks){
    half8 fa[4], fb[4];
    #pragma unroll
    for (int i = 0; i < 4; ++i){
      fa[i] = *(const half8*)(&Qs[(wr*64 + i*16 + lr)*SLDK + ks*32 + lq*8]);
      fb[i] = *(const half8*)(&Ks[(wc*64 + i*16 + lr)*SLDK + ks*32 + lq*8]);
    }
    #pragma unroll
    for (int i = 0; i < 4; ++i)
      #pragma unroll
      for (int j = 0; j < 4; ++j)
        acc[i][j] = __builtin_amdgcn_mfma_f32_16x16x32_f16(fa[i], fb[j], acc[i][j], 0, 0, 0);
  }
  const float scale = 0.10206207f;   // 96^-0.5
  #pragma unroll
  for (int i = 0; i < 4; ++i){
    #pragma unroll
    for (int r = 0; r < 4; ++r){
      int tg = ti*128 + wr*64 + i*16 + lq*4 + r;
      float v = -3.0e38f;
      #pragma unroll
      for (int j = 0; j < 4; ++j){
        int sg = sj*128 + wc*64 + j*16 + lr;
        if (sg <= tg) v = fmaxf(v, acc[i][j][r]*scale);
      }
      #pragma unroll
      for (int off = 1; off < 16; off <<= 1) v = fmaxf(v, __shfl_xor(v, off, 16));
      if (lr == 0) atomicMax(&cgE[(size_t)b*T_ + tg], enc_max(v));
    }
  }
}

__global__ void k_init_cg(unsigned* __restrict__ cgE){
  int i = blockIdx.x*256 + threadIdx.x;
  if (i < M_) cgE[i] = 0u;   // below enc of any finite score; every row gets >=1 update (diag)
}

// ---------------- anchors ----------------
__global__ void k_gather_anchor(const float* __restrict__ x, _Float16* __restrict__ xa){
  int bn = blockIdx.x;                // b*8+n
  int b = bn >> 3, n = bn & 7;
  int pos = n * (T_/NA_);             // 0,256,...,1792
  const float* src = x + (size_t)(b*T_ + pos)*C_;
  for (int c = threadIdx.x; c < C_; c += 256) xa[(size_t)bn*C_ + c] = (_Float16)src[c];
}

__global__ void k_delta(const float* __restrict__ a, const float* __restrict__ scales,
                        float* __restrict__ delta){
  int b = blockIdx.x;
  for (int c = threadIdx.x; c < C_; c += 256){
    float d = 0.f;
    #pragma unroll
    for (int n = 0; n < NA_; ++n)
      d += sigm(scales[n]) * a[(size_t)(b*NA_ + n)*C_ + c];
    delta[(size_t)b*C_ + c] = d;
  }
}

// ---------------- final LayerNorm ----------------
__global__ __launch_bounds__(256) void k_ln(const float* __restrict__ y,
                                            const float* __restrict__ g, const float* __restrict__ be,
                                            float* __restrict__ out){
  int row = blockIdx.x;
  const float* yr = y + (size_t)row*C_;
  int tid = threadIdx.x;
  float v0 = yr[tid], v1 = yr[tid+256], v2 = yr[tid+512];
  float s = v0+v1+v2, ss = v0*v0+v1*v1+v2*v2;
  #pragma unroll
  for (int off = 1; off < 64; off <<= 1){ s += __shfl_xor(s, off); ss += __shfl_xor(ss, off); }
  __shared__ float sb[8];
  int wave = tid >> 6, lane = tid & 63;
  if (lane == 0){ sb[wave] = s; sb[4+wave] = ss; }
  __syncthreads();
  s  = sb[0]+sb[1]+sb[2]+sb[3];
  ss = sb[4]+sb[5]+sb[6]+sb[7];
  float mu  = s * (1.f/C_);
  float var = ss * (1.f/C_) - mu*mu;
  float inv = rsqrtf(var + 1e-5f);
  float* o = out + (size_t)row*C_;
  o[tid]     = (v0-mu)*inv*g[tid]     + be[tid];
  o[tid+256] = (v1-mu)*inv*g[tid+256] + be[tid+256];
  o[tid+512] = (v2-mu)*inv*g[tid+512] + be[tid+512];
}

// ---------------- launch ----------------
extern "C" void kernel_launch(void* const* d_in, const int* in_sizes, int n_in,
                              void* d_out, int out_size, void* d_ws, size_t ws_size,
                              hipStream_t stream){
  (void)in_sizes; (void)n_in; (void)out_size;
  const float* x        = (const float*)d_in[0];
  const float* tau_gate = (const float*)d_in[1];
  const float* tau_fast = (const float*)d_in[2];
  const float* tau_slow = (const float*)d_in[3];
  const float* Wp   = (const float*)d_in[4];  const float* bp    = (const float*)d_in[5];
  const float* Wxf  = (const float*)d_in[6];  const float* bxf   = (const float*)d_in[7];
  const float* Wxs  = (const float*)d_in[8];  const float* bxs   = (const float*)d_in[9];
  const float* Wcf  = (const float*)d_in[10]; const float* Wcs   = (const float*)d_in[11];
  const float* Wq   = (const float*)d_in[12]; const float* Wk    = (const float*)d_in[13];
  const float* Wfast= (const float*)d_in[14]; const float* bfast = (const float*)d_in[15];
  const float* Wslow= (const float*)d_in[16]; const float* bslow = (const float*)d_in[17];
  const float* Wsoma= (const float*)d_in[18]; const float* bsoma = (const float*)d_in[19];
  const float* Wanc = (const float*)d_in[20]; const float* banc  = (const float*)d_in[21];
  const float* ascl = (const float*)d_in[22]; const float* blendr= (const float*)d_in[23];
  const float* lng  = (const float*)d_in[24]; const float* lnb   = (const float*)d_in[25];
  float* out = (float*)d_out;

  char* w = (char*)d_ws;
  auto alloc = [&](size_t bytes)->void*{
    void* p = (void*)w; w += (bytes + 255) & ~(size_t)255; return p;
  };
  _Float16* xh     = (_Float16*)alloc((size_t)M_*C_*2);
  _Float16* xcat   = (_Float16*)alloc((size_t)M_*K2_*2);
  _Float16* wph    = (_Float16*)alloc((size_t)C_*C_*2);
  _Float16* wxfc   = (_Float16*)alloc((size_t)C_*K2_*2);
  _Float16* wxsc   = (_Float16*)alloc((size_t)C_*K2_*2);
  _Float16* wqh    = (_Float16*)alloc((size_t)DK_*C_*2);
  _Float16* wkh    = (_Float16*)alloc((size_t)DK_*C_*2);
  _Float16* wfh    = (_Float16*)alloc((size_t)C_*C_*2);
  _Float16* wsh    = (_Float16*)alloc((size_t)C_*C_*2);
  _Float16* wsomah = (_Float16*)alloc((size_t)C_*C_*2);
  _Float16* wanch  = (_Float16*)alloc((size_t)C_*C_*2);
  _Float16* xph    = (_Float16*)alloc((size_t)M_*C_*2);
  _Float16* wgfh   = (_Float16*)alloc((size_t)M_*C_*2);
  _Float16* wgsh   = (_Float16*)alloc((size_t)M_*C_*2);
  _Float16* qh     = (_Float16*)alloc((size_t)M_*DK_*2);
  _Float16* kh     = (_Float16*)alloc((size_t)M_*DK_*2);
  float*    gbuf   = (float*)alloc((size_t)M_*C_*4);
  unsigned* cgE    = (unsigned*)alloc((size_t)M_*4);
  float* Sg = (float*)alloc((size_t)B_*NCH_*C_*4);
  float* Hg = (float*)alloc((size_t)B_*NCH_*C_*4);
  float* Sf = (float*)alloc((size_t)B_*NCH_*C_*4);
  float* Ss = (float*)alloc((size_t)B_*NCH_*C_*4);
  float* Hf = (float*)alloc((size_t)B_*NCH_*C_*4);
  float* Hs = (float*)alloc((size_t)B_*NCH_*C_*4);
  _Float16* xah  = (_Float16*)alloc((size_t)B_*NA_*C_*2);
  float*    aanc = (float*)alloc((size_t)B_*NA_*C_*4);
  float*    dlt  = (float*)alloc((size_t)B_*C_*4);
  _Float16* cfh = xcat;                       // reuse xcat after G2/G3
  _Float16* csh = xcat + (size_t)M_*C_;
  if ((size_t)(w - (char*)d_ws) > ws_size) return;  // workspace too small

  // 1) casts
  k_cast<<<4096, 256, 0, stream>>>(x, xh, M_*C_);
  k_cast<<<1024, 256, 0, stream>>>(Wp, wph, C_*C_);
  k_cast<<<256, 256, 0, stream>>>(Wq, wqh, DK_*C_);
  k_cast<<<256, 256, 0, stream>>>(Wk, wkh, DK_*C_);
  k_cast<<<1024, 256, 0, stream>>>(Wfast, wfh, C_*C_);
  k_cast<<<1024, 256, 0, stream>>>(Wslow, wsh, C_*C_);
  k_cast<<<1024, 256, 0, stream>>>(Wsoma, wsomah, C_*C_);
  k_cast<<<1024, 256, 0, stream>>>(Wanc, wanch, C_*C_);
  k_cast_cat<<<C_, 256, 0, stream>>>(Wxf, Wcf, wxfc, C_);
  k_cast_cat<<<C_, 256, 0, stream>>>(Wxs, Wcs, wxsc, C_);
  k_xcat_x<<<dim3(3, M_), 256, 0, stream>>>(x, xcat);

  // 2) gate EMA -> xcat[:, C:]
  k_ema_gate_p1<<<B_*NCH_, 256, 0, stream>>>(x, tau_gate, Sg);
  k_ema_p2<<<B_, 256, 0, stream>>>(Sg, Hg, tau_gate, (float)CK_);
  k_ema_gate_p3<<<B_*NCH_, 256, 0, stream>>>(x, tau_gate, Hg, xcat);

  // 3) projections
  k_gemm<<<dim3(64,6), 256, 0, stream>>>(xh, wph, bp, M_, C_, C_, 1, 1, nullptr, xph, nullptr, nullptr);
  k_gemm<<<dim3(64,6), 256, 0, stream>>>(xcat, wxfc, bxf, M_, C_, K2_, 2, 1, nullptr, wgfh, nullptr, nullptr);
  k_gemm<<<dim3(64,6), 256, 0, stream>>>(xcat, wxsc, bxs, M_, C_, K2_, 2, 1, nullptr, wgsh, nullptr, nullptr);
  k_gemm<<<dim3(64,1), 256, 0, stream>>>(xh, wqh, nullptr, M_, DK_, C_, 0, 1, nullptr, qh, nullptr, nullptr);
  k_gemm<<<dim3(64,1), 256, 0, stream>>>(xh, wkh, nullptr, M_, DK_, C_, 0, 1, nullptr, kh, nullptr, nullptr);

  // 4) causal max score -> cg (encoded)
  k_init_cg<<<M_/256, 256, 0, stream>>>(cgE);
  k_score<<<dim3(136, B_), 256, 0, stream>>>(qh, kh, cgE);

  // 5) anchors -> delta
  k_gather_anchor<<<B_*NA_, 256, 0, stream>>>(x, xah);
  k_gemm<<<dim3(1,6), 256, 0, stream>>>(xah, wanch, banc, B_*NA_, C_, C_, 1, 0, aanc, nullptr, nullptr, nullptr);
  k_delta<<<B_, 256, 0, stream>>>(aanc, ascl, dlt);

  // 6) fast/slow EMAs (fused), output already *cg + delta, f16
  k_ema_fs_p1<<<B_*NCH_, 256, 0, stream>>>(xph, wgfh, wgsh, tau_fast, tau_slow, Sf, Ss);
  k_ema_p2<<<B_, 256, 0, stream>>>(Sf, Hf, tau_fast, (float)CK_);
  k_ema_p2<<<B_, 256, 0, stream>>>(Ss, Hs, tau_slow, (float)CK_);
  k_ema_fs_p3<<<B_*NCH_, 256, 0, stream>>>(xph, wgfh, wgsh, tau_fast, tau_slow, Hf, Hs,
                                           cgE, dlt, cfh, csh);

  // 7) gates + soma + blend, fused epilogues into gbuf
  k_gemm<<<dim3(64,6), 256, 0, stream>>>(cfh, wfh, bfast, M_, C_, C_, 2, 0, gbuf, nullptr, nullptr, nullptr);
  k_gemm<<<dim3(64,6), 256, 0, stream>>>(csh, wsh, bslow, M_, C_, C_, 2, 2, gbuf, nullptr, gbuf, blendr);
  k_gemm<<<dim3(64,6), 256, 0, stream>>>(xh, wsomah, bsoma, M_, C_, C_, 1, 3, gbuf, nullptr, gbuf, nullptr);

  // 8) layernorm -> out
  k_ln<<<M_, 256, 0, stream>>>(gbuf, lng, lnb, out);
}

// Round 2
// 404.353 us; speedup vs baseline: 2.2321x; 2.2321x over previous
//
#include <hip/hip_runtime.h>
#include <math.h>

#define B_ 4
#define T_ 2048
#define C_ 768
#define DK_ 96
#define NA_ 8
#define M_ (B_*T_)      /* 8192 */
#define K2_ (2*C_)      /* 1536 */
#define NCH_ 64         /* EMA chunks */
#define CK_ 32          /* EMA chunk len */

typedef __attribute__((ext_vector_type(8))) _Float16 half8;
typedef __attribute__((ext_vector_type(4))) _Float16 half4;
typedef __attribute__((ext_vector_type(4))) float floatx4;

#define AS1 __attribute__((address_space(1)))
#define AS3 __attribute__((address_space(3)))

__device__ __forceinline__ float sigm(float x){ return 1.f/(1.f + expf(-x)); }
__device__ __forceinline__ unsigned enc_max(float f){
  unsigned i = __float_as_uint(f);
  return (i & 0x80000000u) ? ~i : (i | 0x80000000u);
}
__device__ __forceinline__ float dec_max(unsigned u){
  unsigned i = (u & 0x80000000u) ? (u & 0x7FFFFFFFu) : ~u;
  return __uint_as_float(i);
}
__device__ __forceinline__ float alpha_of(const float* tau){
  return expf(-log1pf(expf(tau[0])));
}
__device__ __forceinline__ void gld16(const _Float16* g, _Float16* l){
  __builtin_amdgcn_global_load_lds((const AS1 unsigned int*)g, (AS3 unsigned int*)l, 16, 0, 0);
}

// ---------------- casts ----------------
// x -> xh (f16) and xcat[:, :C]
__global__ void k_cast_x(const float* __restrict__ x, _Float16* __restrict__ xh,
                         _Float16* __restrict__ xcat){
  int i = blockIdx.x*256 + threadIdx.x;       // over M*C/4
  float4 v = ((const float4*)x)[i];
  half4 h = { (_Float16)v.x, (_Float16)v.y, (_Float16)v.z, (_Float16)v.w };
  ((half4*)xh)[i] = h;
  int row = i / 192, c4 = i - row*192;
  *(half4*)(xcat + (size_t)row*K2_ + c4*4) = h;
}

// 4 C x C weights -> wall (f16, concatenated): Wp, Wfast, Wslow, Wsoma
__global__ void k_cast_w4(const float* __restrict__ w0, const float* __restrict__ w1,
                          const float* __restrict__ w2, const float* __restrict__ w3,
                          _Float16* __restrict__ wall){
  int i = blockIdx.x*256 + threadIdx.x;       // over 4*(C*C/4)
  const int per = (C_*C_)/4;                  // 147456
  int s = i / per, j = i - s*per;
  const float* src = s==0?w0 : s==1?w1 : s==2?w2 : w3;
  float4 v = ((const float4*)src)[j];
  half4 h = { (_Float16)v.x, (_Float16)v.y, (_Float16)v.z, (_Float16)v.w };
  ((half4*)wall)[(size_t)s*per + j] = h;
}

// wxfsc (1536x1536 f16): rows<768 -> [Wxf | Wcf], rows>=768 -> [Wxs | Wcs]
__global__ void k_cast_wxfsc(const float* __restrict__ Wxf, const float* __restrict__ Wcf,
                             const float* __restrict__ Wxs, const float* __restrict__ Wcs,
                             _Float16* __restrict__ dst){
  int r = blockIdx.x;
  const float* s0 = (r < C_) ? Wxf + (size_t)r*C_ : Wxs + (size_t)(r-C_)*C_;
  const float* s1 = (r < C_) ? Wcf + (size_t)r*C_ : Wcs + (size_t)(r-C_)*C_;
  int c = threadIdx.x;
  if (c < 192){
    float4 a = ((const float4*)s0)[c];
    float4 b = ((const float4*)s1)[c];
    half4 ha = { (_Float16)a.x,(_Float16)a.y,(_Float16)a.z,(_Float16)a.w };
    half4 hb = { (_Float16)b.x,(_Float16)b.y,(_Float16)b.z,(_Float16)b.w };
    ((half4*)(dst + (size_t)r*K2_))[c] = ha;
    ((half4*)(dst + (size_t)r*K2_ + C_))[c] = hb;
  }
}

// wqk (256x768 f16): rows 0..95 Wq, 96..191 Wk, 192..255 zero. Also zero cgE.
__global__ void k_cast_wqk(const float* __restrict__ Wq, const float* __restrict__ Wk,
                           _Float16* __restrict__ dst, unsigned* __restrict__ cgE){
  int blk = blockIdx.x;
  if (blk >= 256){ cgE[(blk-256)*256 + threadIdx.x] = 0u; return; }
  int r = blk;
  const float* src = (r < 96) ? Wq + (size_t)r*C_ : (r < 192 ? Wk + (size_t)(r-96)*C_ : nullptr);
  #pragma unroll
  for (int k = 0; k < 3; ++k){
    int c = threadIdx.x + k*256;
    dst[(size_t)r*C_ + c] = src ? (_Float16)src[c] : (_Float16)0.f;
  }
}

// ---------------- EMA (chunked scan, NCH=64, CK=32) ----------------
__global__ void k_ema_gate_p1(const float* __restrict__ x, const float* __restrict__ tau,
                              float* __restrict__ S){
  float al = alpha_of(tau);
  int b = blockIdx.x >> 6, ch = blockIdx.x & 63;
  const float* xp = x + (size_t)(b*T_ + ch*CK_)*C_;
  int c = threadIdx.x;
  float s0=0.f, s1=0.f, s2=0.f;
  for (int t = 0; t < CK_; ++t){
    const float* r = xp + (size_t)t*C_;
    s0 = al*s0 + r[c]; s1 = al*s1 + r[c+256]; s2 = al*s2 + r[c+512];
  }
  float* o = S + (size_t)blockIdx.x*C_;
  o[c]=s0; o[c+256]=s1; o[c+512]=s2;
}

__global__ void k_ema_p2(const float* __restrict__ S, float* __restrict__ H,
                         const float* __restrict__ tau){
  int b = blockIdx.x;
  float aCK = expf(-(float)CK_ * log1pf(expf(tau[0])));
  for (int c = threadIdx.x; c < C_; c += 256){
    float h = 0.f;
    for (int ch = 0; ch < NCH_; ++ch){
      size_t idx = (size_t)(b*NCH_ + ch)*C_ + c;
      H[idx] = h;
      h = aCK*h + S[idx];
    }
  }
}

__global__ void k_ema_p2fs(const float* __restrict__ Sf, const float* __restrict__ Ss,
                           float* __restrict__ Hf, float* __restrict__ Hs,
                           const float* __restrict__ tf, const float* __restrict__ ts){
  int which = blockIdx.x >> 2, b = blockIdx.x & 3;
  const float* S = which ? Ss : Sf;
  float* H = which ? Hs : Hf;
  const float* tau = which ? ts : tf;
  float aCK = expf(-(float)CK_ * log1pf(expf(tau[0])));
  for (int c = threadIdx.x; c < C_; c += 256){
    float h = 0.f;
    for (int ch = 0; ch < NCH_; ++ch){
      size_t idx = (size_t)(b*NCH_ + ch)*C_ + c;
      H[idx] = h;
      h = aCK*h + S[idx];
    }
  }
}

__global__ void k_ema_gate_p3(const float* __restrict__ x, const float* __restrict__ tau,
                              const float* __restrict__ H, _Float16* __restrict__ xcat){
  float al = alpha_of(tau);
  int b = blockIdx.x >> 6, ch = blockIdx.x & 63;
  const float* xp = x + (size_t)(b*T_ + ch*CK_)*C_;
  _Float16* op = xcat + (size_t)(b*T_ + ch*CK_)*K2_ + C_;
  int c = threadIdx.x;
  const float* hp = H + (size_t)blockIdx.x*C_;
  float h0 = hp[c], h1 = hp[c+256], h2 = hp[c+512];
  for (int t = 0; t < CK_; ++t){
    const float* r = xp + (size_t)t*C_;
    h0 = al*h0 + r[c]; h1 = al*h1 + r[c+256]; h2 = al*h2 + r[c+512];
    _Float16* o = op + (size_t)t*K2_;
    o[c]=(_Float16)h0; o[c+256]=(_Float16)h1; o[c+512]=(_Float16)h2;
  }
}

// fast+slow pass1: b_f = xp*wg_f, b_s = xp*wg_s; wgfs row: [wg_f(768) | wg_s(768)]
__global__ void k_ema_fs_p1(const _Float16* __restrict__ xp, const _Float16* __restrict__ wgfs,
                            const float* __restrict__ tf, const float* __restrict__ ts,
                            float* __restrict__ Sf, float* __restrict__ Ss){
  float af = alpha_of(tf), as = alpha_of(ts);
  int b = blockIdx.x >> 6, ch = blockIdx.x & 63;
  int t0 = b*T_ + ch*CK_;
  int c = threadIdx.x;
  float f0=0,f1=0,f2=0, s0=0,s1=0,s2=0;
  for (int t = 0; t < CK_; ++t){
    const _Float16* pr = xp + (size_t)(t0+t)*C_;
    const _Float16* wr = wgfs + (size_t)(t0+t)*K2_;
    float p0=(float)pr[c], p1=(float)pr[c+256], p2=(float)pr[c+512];
    f0 = af*f0 + p0*(float)wr[c];       s0 = as*s0 + p0*(float)wr[C_+c];
    f1 = af*f1 + p1*(float)wr[c+256];   s1 = as*s1 + p1*(float)wr[C_+c+256];
    f2 = af*f2 + p2*(float)wr[c+512];   s2 = as*s2 + p2*(float)wr[C_+c+512];
  }
  float* of = Sf + (size_t)blockIdx.x*C_;
  float* os = Ss + (size_t)blockIdx.x*C_;
  of[c]=f0; of[c+256]=f1; of[c+512]=f2;
  os[c]=s0; os[c+256]=s1; os[c+512]=s2;
}

__global__ void k_ema_fs_p3(const _Float16* __restrict__ xp, const _Float16* __restrict__ wgfs,
                            const float* __restrict__ tf, const float* __restrict__ ts,
                            const float* __restrict__ Hf, const float* __restrict__ Hs,
                            const unsigned* __restrict__ cgE, const float* __restrict__ delta,
                            _Float16* __restrict__ cf, _Float16* __restrict__ cs){
  float af = alpha_of(tf), as = alpha_of(ts);
  int b = blockIdx.x >> 6, ch = blockIdx.x & 63;
  int t0 = b*T_ + ch*CK_;
  int c = threadIdx.x;
  const float* dp = delta + (size_t)b*C_;
  float d0 = dp[c], d1 = dp[c+256], d2 = dp[c+512];
  const float* hfp = Hf + (size_t)blockIdx.x*C_;
  const float* hsp = Hs + (size_t)blockIdx.x*C_;
  float f0=hfp[c], f1=hfp[c+256], f2=hfp[c+512];
  float s0=hsp[c], s1=hsp[c+256], s2=hsp[c+512];
  const unsigned* cgp = cgE + t0;
  for (int t = 0; t < CK_; ++t){
    size_t ro = (size_t)(t0+t)*C_;
    const _Float16* pr = xp + ro;
    const _Float16* wr = wgfs + (size_t)(t0+t)*K2_;
    float cgv = sigm(dec_max(cgp[t]));
    float p0=(float)pr[c], p1=(float)pr[c+256], p2=(float)pr[c+512];
    f0 = af*f0 + p0*(float)wr[c];       s0 = as*s0 + p0*(float)wr[C_+c];
    f1 = af*f1 + p1*(float)wr[c+256];   s1 = as*s1 + p1*(float)wr[C_+c+256];
    f2 = af*f2 + p2*(float)wr[c+512];   s2 = as*s2 + p2*(float)wr[C_+c+512];
    cf[ro+c]     = (_Float16)(f0*cgv + d0);
    cf[ro+c+256] = (_Float16)(f1*cgv + d1);
    cf[ro+c+512] = (_Float16)(f2*cgv + d2);
    cs[ro+c]     = (_Float16)(s0*cgv + d0);
    cs[ro+c+256] = (_Float16)(s1*cgv + d1);
    cs[ro+c+512] = (_Float16)(s2*cgv + d2);
  }
}

// ---------------- GEMM tile core (128x128, BK=64, async LDS + XOR swizzle) ----------------
template<int K>
__device__ __forceinline__ void gemm_tile(const _Float16* __restrict__ A, const _Float16* __restrict__ W,
                                          int m0, int n0, _Float16* As, _Float16* Ws,
                                          floatx4 acc[4][4]){
  int tid = threadIdx.x;
  int wave = tid >> 6, lane = tid & 63;
  int wr = wave >> 1, wc = wave & 1;
  int lr = lane & 15, lq = lane >> 4;
  for (int k0 = 0; k0 < K; k0 += 64){
    #pragma unroll
    for (int it = 0; it < 4; ++it){
      int cb = it*256 + wave*64;          // wave-uniform chunk base
      int ck = cb + lane;                 // this lane's chunk
      int row = ck >> 3;
      int kp = (ck & 7) ^ (row & 7);      // XOR swizzle (slot=ck&7 holds global chunk kp)
      gld16(A + (size_t)(m0+row)*K + k0 + kp*8, As + (size_t)cb*8);
      gld16(W + (size_t)(n0+row)*K + k0 + kp*8, Ws + (size_t)cb*8);
    }
    asm volatile("s_waitcnt vmcnt(0)" ::: "memory");
    __syncthreads();
    #pragma unroll
    for (int ks = 0; ks < 2; ++ks){
      half8 fa[4], fb[4];
      int off = (((ks*4 + lq) ^ (lr & 7)) << 3);
      #pragma unroll
      for (int i = 0; i < 4; ++i){
        fa[i] = *(const half8*)(As + (wr*64 + i*16 + lr)*64 + off);
        fb[i] = *(const half8*)(Ws + (wc*64 + i*16 + lr)*64 + off);
      }
      #pragma unroll
      for (int i = 0; i < 4; ++i)
        #pragma unroll
        for (int j = 0; j < 4; ++j)
          acc[i][j] = __builtin_amdgcn_mfma_f32_16x16x32_f16(fa[i], fb[j], acc[i][j], 0, 0, 0);
    }
    __syncthreads();
  }
}

__device__ __forceinline__ void store_tile_f16(floatx4 acc[4][4], _Float16* __restrict__ out, int ldo,
                                               const float* bias, const float* bias2,
                                               int m0, int n0, int act){
  int tid = threadIdx.x;
  int wave = tid >> 6, lane = tid & 63;
  int wr = wave >> 1, wc = wave & 1;
  int lr = lane & 15, lq = lane >> 4;
  #pragma unroll
  for (int i = 0; i < 4; ++i){
    #pragma unroll
    for (int j = 0; j < 4; ++j){
      int col = n0 + wc*64 + j*16 + lr;
      float bv = 0.f;
      if (bias) bv = (bias2 && col >= C_) ? bias2[col - C_] : bias[col];
      #pragma unroll
      for (int r = 0; r < 4; ++r){
        int rowm = m0 + wr*64 + i*16 + lq*4 + r;
        float z = acc[i][j][r] + bv;
        if (act == 1) z = tanhf(z);
        else if (act == 2) z = sigm(z);
        out[(size_t)rowm*ldo + col] = (_Float16)z;
      }
    }
  }
}

// stage 3: xp (tanh), wg_f||wg_s (sigmoid, K=1536), q||k (none, padded N=256)
__global__ __launch_bounds__(256,3) void k_gemm_s3(
    const _Float16* __restrict__ xh, const _Float16* __restrict__ xcat,
    const _Float16* __restrict__ wph, const _Float16* __restrict__ wxfsc,
    const _Float16* __restrict__ wqk,
    const float* __restrict__ bp, const float* __restrict__ bxf, const float* __restrict__ bxs,
    _Float16* __restrict__ xph, _Float16* __restrict__ wgfs, _Float16* __restrict__ qk)
{
  __shared__ _Float16 As[128*64];
  __shared__ _Float16 Ws[128*64];
  floatx4 acc[4][4] = {};
  int m0 = blockIdx.x * 128;
  int ny = blockIdx.y;
  if (ny < 6){
    gemm_tile<C_>(xh, wph, m0, ny*128, As, Ws, acc);
    store_tile_f16(acc, xph, C_, bp, nullptr, m0, ny*128, 1);
  } else if (ny < 18){
    int n0 = (ny-6)*128;
    gemm_tile<K2_>(xcat, wxfsc, m0, n0, As, Ws, acc);
    store_tile_f16(acc, wgfs, K2_, bxf, bxs, m0, n0, 2);
  } else {
    int n0 = (ny-18)*128;
    gemm_tile<C_>(xh, wqk, m0, n0, As, Ws, acc);
    store_tile_f16(acc, qk, 256, nullptr, nullptr, m0, n0, 0);
  }
}

// stage 7: gf (sigmoid), gs (sigmoid), soma (tanh) -> f16 buffers
__global__ __launch_bounds__(256,3) void k_gemm_s7(
    const _Float16* __restrict__ cf, const _Float16* __restrict__ cs, const _Float16* __restrict__ xh,
    const _Float16* __restrict__ wfh, const _Float16* __restrict__ wsh, const _Float16* __restrict__ wsomah,
    const float* __restrict__ bf, const float* __restrict__ bs, const float* __restrict__ bso,
    _Float16* __restrict__ gfb, _Float16* __restrict__ gsb, _Float16* __restrict__ somab)
{
  __shared__ _Float16 As[128*64];
  __shared__ _Float16 Ws[128*64];
  floatx4 acc[4][4] = {};
  int m0 = blockIdx.x * 128;
  int s = blockIdx.y / 6, nt = (blockIdx.y % 6) * 128;
  const _Float16* A = (s==0) ? cf : (s==1) ? cs : xh;
  const _Float16* W = (s==0) ? wfh : (s==1) ? wsh : wsomah;
  const float* bias = (s==0) ? bf : (s==1) ? bs : bso;
  _Float16* out = (s==0) ? gfb : (s==1) ? gsb : somab;
  gemm_tile<C_>(A, W, m0, nt, As, Ws, acc);
  store_tile_f16(acc, out, C_, bias, nullptr, m0, nt, (s==2) ? 1 : 2);
}

// ---------------- causal max-score (MFMA); qk row stride 256 (q at 0, k at 96) ----------------
#define SLDK 104
__global__ __launch_bounds__(256,2) void k_score(
    const _Float16* __restrict__ qk, unsigned* __restrict__ cgE)
{
  __shared__ _Float16 Qs[128*SLDK];
  __shared__ _Float16 Ks[128*SLDK];
  int b = blockIdx.y;
  int p = blockIdx.x;
  int ti = (int)((sqrtf(8.f*p + 1.f) - 1.f)*0.5f);
  while ((ti+1)*(ti+2)/2 <= p) ++ti;
  while (ti*(ti+1)/2 > p) --ti;
  int sj = p - ti*(ti+1)/2;

  int tid = threadIdx.x;
  const _Float16* qg = qk + (size_t)(b*T_ + ti*128)*256;
  const _Float16* kg = qk + (size_t)(b*T_ + sj*128)*256 + 96;
  #pragma unroll
  for (int r = 0; r < 6; ++r){
    int ci = tid + r*256;
    int row = ci / 12, kp = ci % 12;
    *(uint4*)(&Qs[row*SLDK + kp*8]) = *(const uint4*)(qg + (size_t)row*256 + kp*8);
    *(uint4*)(&Ks[row*SLDK + kp*8]) = *(const uint4*)(kg + (size_t)row*256 + kp*8);
  }
  __syncthreads();

  int wave = tid >> 6, lane = tid & 63;
  int wr = wave >> 1, wc = wave & 1;
  int lr = lane & 15, lq = lane >> 4;
  floatx4 acc[4][4] = {};
  #pragma unroll
  for (int ks = 0; ks < 3; ++ks){
    half8 fa[4], fb[4];
    #pragma unroll
    for (int i = 0; i < 4; ++i){
      fa[i] = *(const half8*)(&Qs[(wr*64 + i*16 + lr)*SLDK + ks*32 + lq*8]);
      fb[i] = *(const half8*)(&Ks[(wc*64 + i*16 + lr)*SLDK + ks*32 + lq*8]);
    }
    #pragma unroll
    for (int i = 0; i < 4; ++i)
      #pragma unroll
      for (int j = 0; j < 4; ++j)
        acc[i][j] = __builtin_amdgcn_mfma_f32_16x16x32_f16(fa[i], fb[j], acc[i][j], 0, 0, 0);
  }
  const float scale = 0.10206207f;   // 96^-0.5
  #pragma unroll
  for (int i = 0; i < 4; ++i){
    #pragma unroll
    for (int r = 0; r < 4; ++r){
      int tg = ti*128 + wr*64 + i*16 + lq*4 + r;
      float v = -3.0e38f;
      #pragma unroll
      for (int j = 0; j < 4; ++j){
        int sg = sj*128 + wc*64 + j*16 + lr;
        if (sg <= tg) v = fmaxf(v, acc[i][j][r]*scale);
      }
      #pragma unroll
      for (int off = 1; off < 16; off <<= 1) v = fmaxf(v, __shfl_xor(v, off, 16));
      if (lr == 0) atomicMax(&cgE[(size_t)b*T_ + tg], enc_max(v));
    }
  }
}

// ---------------- anchors: delta[b,c] = sum_n sig(scale_n)*tanh(x[b,pos_n]@Wanc^T + banc)[c] ----------------
__global__ __launch_bounds__(256) void k_anchor(const float* __restrict__ x, const float* __restrict__ Wanc,
                        const float* __restrict__ banc, const float* __restrict__ scales,
                        float* __restrict__ delta){
  __shared__ float xs[NA_*C_];
  __shared__ float part[NA_*128];
  int b = blockIdx.y, ct = blockIdx.x;
  int tid = threadIdx.x;
  for (int i = tid; i < NA_*C_; i += 256){
    int n = i / C_, c = i - n*C_;
    xs[i] = x[(size_t)(b*T_ + n*(T_/NA_))*C_ + c];
  }
  __syncthreads();
  int col = ct*128 + (tid & 127), kh = tid >> 7;
  float acc[NA_] = {0,0,0,0,0,0,0,0};
  const float* wrow = Wanc + (size_t)col*C_ + kh*384;
  const float* xk = xs + kh*384;
  for (int k = 0; k < 384; ++k){
    float wv = wrow[k];
    #pragma unroll
    for (int n = 0; n < NA_; ++n) acc[n] += xk[n*C_ + k]*wv;
  }
  if (kh){
    #pragma unroll
    for (int n = 0; n < NA_; ++n) part[n*128 + (tid & 127)] = acc[n];
  }
  __syncthreads();
  if (!kh){
    float d = 0.f;
    float bv = banc[col];
    #pragma unroll
    for (int n = 0; n < NA_; ++n){
      float a = tanhf(acc[n] + part[n*128 + (tid & 127)] + bv);
      d += sigm(scales[n]) * a;
    }
    delta[(size_t)b*C_ + col] = d;
  }
}

// ---------------- fused blend + soma-mul + LayerNorm ----------------
__global__ __launch_bounds__(256) void k_ln(const _Float16* __restrict__ gfb,
                                            const _Float16* __restrict__ gsb,
                                            const _Float16* __restrict__ somab,
                                            const float* __restrict__ blendr,
                                            const float* __restrict__ g, const float* __restrict__ be,
                                            float* __restrict__ out){
  int row = blockIdx.x;
  int tid = threadIdx.x;
  float bl = sigm(blendr[0]);
  size_t base = (size_t)row*C_;
  float v0, v1, v2;
  {
    float gf = (float)gfb[base+tid],     gs = (float)gsb[base+tid],     so = (float)somab[base+tid];
    v0 = so * (gf + bl*(gs - gf));
    gf = (float)gfb[base+tid+256]; gs = (float)gsb[base+tid+256]; so = (float)somab[base+tid+256];
    v1 = so * (gf + bl*(gs - gf));
    gf = (float)gfb[base+tid+512]; gs = (float)gsb[base+tid+512]; so = (float)somab[base+tid+512];
    v2 = so * (gf + bl*(gs - gf));
  }
  float s = v0+v1+v2, ss = v0*v0+v1*v1+v2*v2;
  #pragma unroll
  for (int off = 1; off < 64; off <<= 1){ s += __shfl_xor(s, off); ss += __shfl_xor(ss, off); }
  __shared__ float sb[8];
  int wave = tid >> 6, lane = tid & 63;
  if (lane == 0){ sb[wave] = s; sb[4+wave] = ss; }
  __syncthreads();
  s  = sb[0]+sb[1]+sb[2]+sb[3];
  ss = sb[4]+sb[5]+sb[6]+sb[7];
  float mu  = s * (1.f/C_);
  float var = ss * (1.f/C_) - mu*mu;
  float inv = rsqrtf(var + 1e-5f);
  out[base+tid]     = (v0-mu)*inv*g[tid]     + be[tid];
  out[base+tid+256] = (v1-mu)*inv*g[tid+256] + be[tid+256];
  out[base+tid+512] = (v2-mu)*inv*g[tid+512] + be[tid+512];
}

// ---------------- launch ----------------
extern "C" void kernel_launch(void* const* d_in, const int* in_sizes, int n_in,
                              void* d_out, int out_size, void* d_ws, size_t ws_size,
                              hipStream_t stream){
  (void)in_sizes; (void)n_in; (void)out_size;
  const float* x        = (const float*)d_in[0];
  const float* tau_gate = (const float*)d_in[1];
  const float* tau_fast = (const float*)d_in[2];
  const float* tau_slow = (const float*)d_in[3];
  const float* Wp   = (const float*)d_in[4];  const float* bp    = (const float*)d_in[5];
  const float* Wxf  = (const float*)d_in[6];  const float* bxf   = (const float*)d_in[7];
  const float* Wxs  = (const float*)d_in[8];  const float* bxs   = (const float*)d_in[9];
  const float* Wcf  = (const float*)d_in[10]; const float* Wcs   = (const float*)d_in[11];
  const float* Wq   = (const float*)d_in[12]; const float* Wk    = (const float*)d_in[13];
  const float* Wfast= (const float*)d_in[14]; const float* bfast = (const float*)d_in[15];
  const float* Wslow= (const float*)d_in[16]; const float* bslow = (const float*)d_in[17];
  const float* Wsoma= (const float*)d_in[18]; const float* bsoma = (const float*)d_in[19];
  const float* Wanc = (const float*)d_in[20]; const float* banc  = (const float*)d_in[21];
  const float* ascl = (const float*)d_in[22]; const float* blendr= (const float*)d_in[23];
  const float* lng  = (const float*)d_in[24]; const float* lnb   = (const float*)d_in[25];
  float* out = (float*)d_out;

  char* w = (char*)d_ws;
  auto alloc = [&](size_t bytes)->void*{
    void* p = (void*)w; w += (bytes + 255) & ~(size_t)255; return p;
  };
  _Float16* xh    = (_Float16*)alloc((size_t)M_*C_*2);
  _Float16* xcat  = (_Float16*)alloc((size_t)M_*K2_*2);
  _Float16* wall  = (_Float16*)alloc((size_t)4*C_*C_*2);
  _Float16* wxfsc = (_Float16*)alloc((size_t)K2_*K2_*2);
  _Float16* wqk   = (_Float16*)alloc((size_t)256*C_*2);
  _Float16* xph   = (_Float16*)alloc((size_t)M_*C_*2);
  _Float16* wgfs  = (_Float16*)alloc((size_t)M_*K2_*2);
  _Float16* qk    = (_Float16*)alloc((size_t)M_*256*2);
  unsigned* cgE   = (unsigned*)alloc((size_t)M_*4);
  float* Sg = (float*)alloc((size_t)B_*NCH_*C_*4);
  float* Hg = (float*)alloc((size_t)B_*NCH_*C_*4);
  float* Sf = (float*)alloc((size_t)B_*NCH_*C_*4);
  float* Ss = (float*)alloc((size_t)B_*NCH_*C_*4);
  float* Hf = (float*)alloc((size_t)B_*NCH_*C_*4);
  float* Hs = (float*)alloc((size_t)B_*NCH_*C_*4);
  float* dlt = (float*)alloc((size_t)B_*C_*4);
  // reuse regions (stream-ordered, producer consumed before overwrite):
  _Float16* cfh   = xcat;                      // cf/cs overwrite xcat after stage-3 GEMM
  _Float16* csh   = xcat + (size_t)M_*C_;
  _Float16* gfb   = wgfs;                      // gf/gs overwrite wgfs after ema_fs_p3
  _Float16* gsb   = wgfs + (size_t)M_*C_;
  _Float16* somab = xph;                       // soma overwrites xph (consumed by ema_fs)
  if ((size_t)(w - (char*)d_ws) > ws_size) return;

  const _Float16* wph    = wall;
  const _Float16* wfh    = wall + (size_t)C_*C_;
  const _Float16* wsh    = wall + (size_t)2*C_*C_;
  const _Float16* wsomah = wall + (size_t)3*C_*C_;

  // casts
  k_cast_x    <<<(M_*C_/4)/256, 256, 0, stream>>>(x, xh, xcat);
  k_cast_w4   <<<(4*C_*C_/4)/256, 256, 0, stream>>>(Wp, Wfast, Wslow, Wsoma, wall);
  k_cast_wxfsc<<<K2_, 256, 0, stream>>>(Wxf, Wcf, Wxs, Wcs, wxfsc);
  k_cast_wqk  <<<288, 256, 0, stream>>>(Wq, Wk, wqk, cgE);

  // gate EMA -> xcat[:, C:]
  k_ema_gate_p1<<<B_*NCH_, 256, 0, stream>>>(x, tau_gate, Sg);
  k_ema_p2     <<<B_, 256, 0, stream>>>(Sg, Hg, tau_gate);
  k_ema_gate_p3<<<B_*NCH_, 256, 0, stream>>>(x, tau_gate, Hg, xcat);

  // stage 3: xp + wg_f||wg_s + q||k in one launch
  k_gemm_s3<<<dim3(M_/128, 20), 256, 0, stream>>>(xh, xcat, wph, wxfsc, wqk,
                                                  bp, bxf, bxs, xph, wgfs, qk);

  // causal max score
  k_score<<<dim3(136, B_), 256, 0, stream>>>(qk, cgE);

  // anchors
  k_anchor<<<dim3(C_/128, B_), 256, 0, stream>>>(x, Wanc, banc, ascl, dlt);

  // fast/slow EMAs (fused); output = h*cg + delta (f16)
  k_ema_fs_p1<<<B_*NCH_, 256, 0, stream>>>(xph, wgfs, tau_fast, tau_slow, Sf, Ss);
  k_ema_p2fs <<<2*B_, 256, 0, stream>>>(Sf, Ss, Hf, Hs, tau_fast, tau_slow);
  k_ema_fs_p3<<<B_*NCH_, 256, 0, stream>>>(xph, wgfs, tau_fast, tau_slow, Hf, Hs,
                                           cgE, dlt, cfh, csh);

  // stage 7: gf + gs + soma in one launch
  k_gemm_s7<<<dim3(M_/128, 18), 256, 0, stream>>>(cfh, csh, xh, wfh, wsh, wsomah,
                                                  bfast, bslow, bsoma, gfb, gsb, somab);

  // fused blend + mul + LN
  k_ln<<<M_, 256, 0, stream>>>(gfb, gsb, somab, blendr, lng, lnb, out);
}